// Round 1
// baseline (1497.793 us; speedup 1.0000x reference)
//
#include <hip/hip_runtime.h>
#include <hip/hip_bf16.h>

#define E_EDGES 262144
#define N_NODES 16384

typedef short bf16x8 __attribute__((ext_vector_type(8)));
typedef float f32x4 __attribute__((ext_vector_type(4)));

static __device__ __forceinline__ short f2bf(float f) {
    union { float f; unsigned u; } v; v.f = f;
    unsigned r = v.u + 0x7FFFu + ((v.u >> 16) & 1u);
    return (short)(r >> 16);
}
static __device__ __forceinline__ float bf2f(short s) {
    union { unsigned u; float f; } v;
    v.u = ((unsigned)(unsigned short)s) << 16;
    return v.f;
}

// ---------------- weight prep: bf16 transposed copies ----------------
// WkT[c*128+k]  = Wk[k*512+c]            (512 x 128)
// WenvT[c*128+k]= W_env[k*64+c]          (64 x 128)
// WcatT[c*96+k] = [W_mix | W_sc][k][c]   (256 x 96, k>=80 zero-padded)
__global__ void kprep(const float* __restrict__ Wk, const float* __restrict__ Wenv,
                      const float* __restrict__ Wmix, const float* __restrict__ Wsc,
                      short* __restrict__ WkT, short* __restrict__ WenvT,
                      short* __restrict__ WcatT) {
    int idx = blockIdx.x * 256 + threadIdx.x;
    if (idx < 65536) {
        int c = idx >> 7, k = idx & 127;
        WkT[idx] = f2bf(Wk[k * 512 + c]);
    } else if (idx < 65536 + 8192) {
        int o = idx - 65536;
        int c = o >> 7, k = o & 127;
        WenvT[o] = f2bf(Wenv[k * 64 + c]);
    } else {
        int o = idx - (65536 + 8192);
        int c = o / 96, k = o - c * 96;
        float v = 0.f;
        if (k < 80) v = (c < 128) ? Wmix[k * 128 + c] : Wsc[k * 128 + (c - 128)];
        WcatT[o] = f2bf(v);
    }
}

// ---------------- Qn = node_invariants @ Wq  (N x 512, fp32) ----------------
__global__ void kqn(const float* __restrict__ ninv, const float* __restrict__ Wq,
                    float* __restrict__ Qn) {
    __shared__ float ni[8 * 68];
    int nBase = blockIdx.x * 8;
    int tid = threadIdx.x;
    for (int idx = tid; idx < 512; idx += 256) {
        int n = idx >> 6, j = idx & 63;
        ni[n * 68 + j] = ninv[(nBase + n) * 64 + j];
    }
    __syncthreads();
    float a0[8] = {0,0,0,0,0,0,0,0};
    float a1[8] = {0,0,0,0,0,0,0,0};
    for (int j = 0; j < 64; ++j) {
        float w0 = Wq[j * 512 + tid];
        float w1 = Wq[j * 512 + tid + 256];
#pragma unroll
        for (int n = 0; n < 8; ++n) {
            float s = ni[n * 68 + j];
            a0[n] += s * w0;
            a1[n] += s * w1;
        }
    }
#pragma unroll
    for (int n = 0; n < 8; ++n) {
        Qn[(nBase + n) * 512 + tid] = a0[n];
        Qn[(nBase + n) * 512 + tid + 256] = a1[n];
    }
}

// ---------------- main edge kernel 1: g (silu), logits -> z, denom ----------------
// block = 256 threads (4 waves), 16 edges per block.
// Wave w: g col-tile [w*16, w*16+16), then logits for m in [w*8, w*8+8).
__launch_bounds__(256)
__global__ void kmain1(const float* __restrict__ sl, const int* __restrict__ ec,
                       const float* __restrict__ Qn, const short* __restrict__ WkT,
                       const short* __restrict__ WenvT, const float* __restrict__ benv,
                       float* __restrict__ zbuf, short* __restrict__ gbuf,
                       float* __restrict__ denom) {
    __shared__ short slb[16 * 136];   // bf16 sl tile, padded (272B row stride)
    __shared__ int cn[16];
    int tid = threadIdx.x;
    int eBase = blockIdx.x * 16;
    for (int idx = tid; idx < 2048; idx += 256) {
        int e = idx >> 7, j = idx & 127;
        slb[e * 136 + j] = f2bf(sl[(eBase + e) * 128 + j]);
    }
    if (tid < 16) cn[tid] = ec[eBase + tid];
    __syncthreads();

    int lane = tid & 63, wv = tid >> 6;
    int r = lane & 15, q = lane >> 4;

    // A fragments (edges x K=128), shared by g-phase and all m
    bf16x8 af[4];
#pragma unroll
    for (int kk = 0; kk < 4; ++kk)
        af[kk] = *(const bf16x8*)&slb[r * 136 + kk * 32 + q * 8];

    // ---- g = silu(sl @ W_env + b_env), col tile per wave ----
    {
        f32x4 acc = {0.f, 0.f, 0.f, 0.f};
#pragma unroll
        for (int kk = 0; kk < 4; ++kk) {
            bf16x8 bb = *(const bf16x8*)&WenvT[(wv * 16 + r) * 128 + kk * 32 + q * 8];
            acc = __builtin_amdgcn_mfma_f32_16x16x32_bf16(af[kk], bb, acc, 0, 0, 0);
        }
        int gcol = wv * 16 + r;
        float bias = benv[gcol];
#pragma unroll
        for (int reg = 0; reg < 4; ++reg) {
            int e = q * 4 + reg;
            float x = acc[reg] + bias;
            float gv = x / (1.f + __expf(-x));
            gbuf[(eBase + e) * 64 + gcol] = f2bf(gv);
        }
    }

    // ---- logits: C = sl @ Wk[:, m*16:m*16+16], dot with gathered Q over d ----
    for (int mi = 0; mi < 8; ++mi) {
        int m = wv * 8 + mi;
        f32x4 acc = {0.f, 0.f, 0.f, 0.f};
#pragma unroll
        for (int kk = 0; kk < 4; ++kk) {
            bf16x8 bb = *(const bf16x8*)&WkT[(m * 16 + r) * 128 + kk * 32 + q * 8];
            acc = __builtin_amdgcn_mfma_f32_16x16x32_bf16(af[kk], bb, acc, 0, 0, 0);
        }
        // C layout: col(d) = lane&15 = r, row(e) = q*4 + reg
        float p[4];
#pragma unroll
        for (int reg = 0; reg < 4; ++reg) {
            int e = q * 4 + reg;
            float qv = Qn[cn[e] * 512 + m * 16 + r];
            p[reg] = acc[reg] * qv;
        }
#pragma unroll
        for (int off = 1; off < 16; off <<= 1) {
#pragma unroll
            for (int reg = 0; reg < 4; ++reg)
                p[reg] += __shfl_xor(p[reg], off, 16);
        }
        if (r == 0) {
#pragma unroll
            for (int reg = 0; reg < 4; ++reg) {
                int e = q * 4 + reg;
                float l = p[reg] * 0.25f;           // INV_SQRTD
                l = fminf(5.f, fmaxf(-5.f, l));     // clip
                float z = __expf(l);                // bounded, no max needed
                zbuf[(eBase + e) * 32 + m] = z;
                atomicAdd(&denom[cn[e] * 32 + m], z);
            }
        }
    }
}

// ---------------- env scatter: env_nodes += equiv*g*attn ----------------
__global__ void kenv(const float* __restrict__ equiv, const int* __restrict__ ec,
                     const float* __restrict__ zbuf, const short* __restrict__ gbuf,
                     const float* __restrict__ denom, float* __restrict__ envn) {
    int idx = blockIdx.x * 256 + threadIdx.x;   // (e, m)
    int e = idx >> 5, m = idx & 31;
    int c = ec[e];
    float attn = zbuf[idx] / denom[c * 32 + m];
    short2 g2 = *(const short2*)&gbuf[e * 64 + 2 * m];
    float g0 = bf2f(g2.x) * attn;
    float g1 = bf2f(g2.y) * attn;
    float4 eq = *(const float4*)&equiv[e * 128 + m * 4];
    float* dst = &envn[c * 128 + m * 4];
    atomicAdd(dst + 0, eq.x * g0);
    atomicAdd(dst + 1, eq.y * g1);
    atomicAdd(dst + 2, eq.z * g1);
    atomicAdd(dst + 3, eq.w * g1);
}

// ---------------- per-node SO3 layernorm (in place) ----------------
__global__ void kln(float* __restrict__ envn) {
    int tid = threadIdx.x;
    int wv = tid >> 6, lane = tid & 63;
    int node = blockIdx.x * 8 + wv * 2 + (lane >> 5);
    int m = lane & 31;
    float4 v = *(float4*)&envn[node * 128 + m * 4];
    float s0 = v.x * v.x;
    float s1 = v.y * v.y + v.z * v.z + v.w * v.w;
#pragma unroll
    for (int off = 1; off < 32; off <<= 1) {
        s0 += __shfl_xor(s0, off, 32);
        s1 += __shfl_xor(s1, off, 32);
    }
    float i0 = rsqrtf(s0 * (1.f / 32.f) + 1e-6f);
    float i1 = rsqrtf(s1 * (1.f / 96.f) + 1e-6f);
    v.x *= i0; v.y *= i1; v.z *= i1; v.w *= i1;
    *(float4*)&envn[node * 128 + m * 4] = v;
}

// ---------------- final: tp, per-edge LN, feats, mix|sc GEMM, outputs ----------------
__launch_bounds__(256)
__global__ void kfinal(const float* __restrict__ sl, const float* __restrict__ equiv,
                       const float* __restrict__ econd, const int* __restrict__ ec,
                       const float* __restrict__ envn, const short* __restrict__ WcatT,
                       const float* __restrict__ bmix, const float* __restrict__ bsc,
                       const float* __restrict__ ucp, float* __restrict__ out) {
    __shared__ float eqlds[16 * 132];
    __shared__ float envl[16 * 132];
    __shared__ float mixl[16 * 132];
    __shared__ float condl[16 * 16];
    __shared__ short featb[16 * 104];   // bf16 feats, K padded to 96 (+8 row pad)
    __shared__ int cn[16];

    int tid = threadIdx.x;
    int eBase = blockIdx.x * 16;
    if (tid < 16) cn[tid] = ec[eBase + tid];
    for (int idx = tid; idx < 2048; idx += 256) {
        int e = idx >> 7, j = idx & 127;
        eqlds[e * 132 + j] = equiv[(eBase + e) * 128 + j];
    }
    {
        int e = tid >> 4, j = tid & 15;
        condl[tid] = econd[(eBase + e) * 16 + j];
    }
    float uc = ucp[0];
    float c_old = rsqrtf(uc * uc + 1.f);
    float c_new = uc * c_old;
    __syncthreads();
    for (int idx = tid; idx < 2048; idx += 256) {
        int e = idx >> 7, j = idx & 127;
        envl[e * 132 + j] = envn[cn[e] * 128 + j];
    }
    __syncthreads();

    // ---- phase 1: tensor product + per-edge SO3 LN, feats (kept in registers) ----
    int e = tid >> 4, i = tid & 15;
    float tp[2][8];
    {
        float s0 = 0, s1 = 0, s2 = 0, s3 = 0;
#pragma unroll
        for (int t2 = 0; t2 < 2; ++t2) {
            int m = i * 2 + t2;
            float4 x = *(const float4*)&eqlds[e * 132 + m * 4];
            float4 y = *(const float4*)&envl[e * 132 + m * 4];
            tp[t2][0] = x.x * y.x;
            tp[t2][1] = x.x * y.y; tp[t2][2] = x.x * y.z; tp[t2][3] = x.x * y.w;
            tp[t2][4] = x.y * y.x; tp[t2][5] = x.z * y.x; tp[t2][6] = x.w * y.x;
            tp[t2][7] = (x.y * y.y + x.z * y.z + x.w * y.w) * 0.57735026919f;
            s0 += tp[t2][0] * tp[t2][0];
            s1 += tp[t2][1] * tp[t2][1] + tp[t2][2] * tp[t2][2] + tp[t2][3] * tp[t2][3];
            s2 += tp[t2][4] * tp[t2][4] + tp[t2][5] * tp[t2][5] + tp[t2][6] * tp[t2][6];
            s3 += tp[t2][7] * tp[t2][7];
        }
#pragma unroll
        for (int off = 1; off < 16; off <<= 1) {
            s0 += __shfl_xor(s0, off, 16);
            s1 += __shfl_xor(s1, off, 16);
            s2 += __shfl_xor(s2, off, 16);
            s3 += __shfl_xor(s3, off, 16);
        }
        float i0 = rsqrtf(s0 * (1.f / 32.f) + 1e-6f);
        float i1 = rsqrtf(s1 * (1.f / 96.f) + 1e-6f);
        float i2 = rsqrtf(s2 * (1.f / 96.f) + 1e-6f);
        float i3 = rsqrtf(s3 * (1.f / 32.f) + 1e-6f);
#pragma unroll
        for (int t2 = 0; t2 < 2; ++t2) {
            tp[t2][0] *= i0;
            tp[t2][1] *= i1; tp[t2][2] *= i1; tp[t2][3] *= i1;
            tp[t2][4] *= i2; tp[t2][5] *= i2; tp[t2][6] *= i2;
            tp[t2][7] *= i3;
            int m = i * 2 + t2;
            featb[e * 104 + m] = f2bf(tp[t2][0]);
            featb[e * 104 + 32 + m] = f2bf(tp[t2][7]);
        }
        featb[e * 104 + 64 + i] = f2bf(condl[e * 16 + i]);
        featb[e * 104 + 80 + i] = 0;
    }
    __syncthreads();

    // ---- phase 2: [mix | new_scalar] = feats @ WcatT (K=96), MFMA ----
    int lane = tid & 63, wv = tid >> 6;
    int r = lane & 15, q = lane >> 4;
    bf16x8 af[3];
#pragma unroll
    for (int kk = 0; kk < 3; ++kk)
        af[kk] = *(const bf16x8*)&featb[r * 104 + kk * 32 + q * 8];
#pragma unroll
    for (int ct4 = 0; ct4 < 4; ++ct4) {
        int ct = wv * 4 + ct4;
        f32x4 acc = {0.f, 0.f, 0.f, 0.f};
#pragma unroll
        for (int kk = 0; kk < 3; ++kk) {
            bf16x8 bb = *(const bf16x8*)&WcatT[(ct * 16 + r) * 96 + kk * 32 + q * 8];
            acc = __builtin_amdgcn_mfma_f32_16x16x32_bf16(af[kk], bb, acc, 0, 0, 0);
        }
        int colg = ct * 16 + r;
        if (colg < 128) {
            float bias = bmix[colg];
#pragma unroll
            for (int reg = 0; reg < 4; ++reg) {
                int ee = q * 4 + reg;
                mixl[ee * 132 + colg] = acc[reg] + bias;
            }
        } else {
            int j = colg - 128;
            float bias = bsc[j];
#pragma unroll
            for (int reg = 0; reg < 4; ++reg) {
                int ee = q * 4 + reg;
                int ge = eBase + ee;
                out[ge * 128 + j] = c_old * sl[ge * 128 + j] + c_new * (acc[reg] + bias);
            }
        }
    }
    __syncthreads();

    // ---- phase 3: new_equiv + residual ----
    float* outeq = out + (size_t)E_EDGES * 128;
#pragma unroll
    for (int t2 = 0; t2 < 2; ++t2) {
        int m = i * 2 + t2;
        float4 mx = *(const float4*)&mixl[e * 132 + m * 4];
        float4 eq = *(const float4*)&eqlds[e * 132 + m * 4];
        float4 o;
        o.x = c_old * eq.x + c_new * (mx.x * tp[t2][0] + mx.y * tp[t2][7]);
        o.y = c_old * eq.y + c_new * (mx.z * tp[t2][1] + mx.w * tp[t2][4]);
        o.z = c_old * eq.z + c_new * (mx.z * tp[t2][2] + mx.w * tp[t2][5]);
        o.w = c_old * eq.w + c_new * (mx.z * tp[t2][3] + mx.w * tp[t2][6]);
        *(float4*)&outeq[(size_t)(eBase + e) * 128 + m * 4] = o;
    }
}

extern "C" void kernel_launch(void* const* d_in, const int* in_sizes, int n_in,
                              void* d_out, int out_size, void* d_ws, size_t ws_size,
                              hipStream_t stream) {
    const float* sl    = (const float*)d_in[0];
    const float* eqv   = (const float*)d_in[1];
    const float* ninv  = (const float*)d_in[2];
    const float* econd = (const float*)d_in[3];
    const float* uc    = (const float*)d_in[4];
    const float* Wenv  = (const float*)d_in[5];
    const float* benv  = (const float*)d_in[6];
    const float* Wq    = (const float*)d_in[7];
    const float* Wk    = (const float*)d_in[8];
    const float* Wmix  = (const float*)d_in[9];
    const float* bmix  = (const float*)d_in[10];
    const float* Wsc   = (const float*)d_in[11];
    const float* bsc   = (const float*)d_in[12];
    const int*   ec    = (const int*)d_in[13];
    float* out = (float*)d_out;

    float* ws = (float*)d_ws;
    float* Qn    = ws;                                  // N*512
    float* zbuf  = Qn + (size_t)N_NODES * 512;          // E*32
    float* denom = zbuf + (size_t)E_EDGES * 32;         // N*32
    float* envn  = denom + (size_t)N_NODES * 32;        // N*128
    short* gbuf  = (short*)(envn + (size_t)N_NODES * 128); // E*64 bf16
    short* WkT   = gbuf + (size_t)E_EDGES * 64;         // 512*128
    short* WenvT = WkT + 65536;                          // 64*128
    short* WcatT = WenvT + 8192;                         // 256*96

    // zero denom + env_nodes (adjacent)
    hipMemsetAsync(denom, 0, (size_t)(N_NODES * 32 + N_NODES * 128) * sizeof(float), stream);

    kprep<<<384, 256, 0, stream>>>(Wk, Wenv, Wmix, Wsc, WkT, WenvT, WcatT);
    kqn<<<N_NODES / 8, 256, 0, stream>>>(ninv, Wq, Qn);
    kmain1<<<E_EDGES / 16, 256, 0, stream>>>(sl, ec, Qn, WkT, WenvT, benv, zbuf, gbuf, denom);
    kenv<<<(E_EDGES * 32) / 256, 256, 0, stream>>>(eqv, ec, zbuf, gbuf, denom, envn);
    kln<<<N_NODES / 8, 256, 0, stream>>>(envn);
    kfinal<<<E_EDGES / 16, 256, 0, stream>>>(sl, eqv, econd, ec, envn, WcatT, bmix, bsc, uc, out);
}